// Round 7
// baseline (171.693 us; speedup 1.0000x reference)
//
#include <hip/hip_runtime.h>

typedef __attribute__((ext_vector_type(8))) short short8;
typedef __attribute__((ext_vector_type(4))) float f32x4;

// Pack two fp32 into two bf16 (round-half-up) in one u32: 3 VALU ops per pair.
__device__ __forceinline__ unsigned pack2bf(float x0, float x1) {
    unsigned u0 = __float_as_uint(x0) + 0x8000u;
    unsigned u1 = __float_as_uint(x1) + 0x8000u;
    return __builtin_amdgcn_perm(u1, u0, 0x07060302u);  // {u1.hi16, u0.hi16}
}

// Convert W (mul x mul, row-major [u][w]) to bf16, fold in scale, store in
// MFMA-B-fragment order: frag (cb,kb) holds B[k][n] for n=cb*16+(l&15),
// k=kb*32+(l>>4)*8+j ; element addr = ((cb*NKB+kb)*64 + lane)*8 + j.
__device__ __forceinline__ void prep_one(const float* __restrict__ W,
                                         unsigned short* __restrict__ dst,
                                         int mul, int shift, float scale, int idx) {
    if (idx >= mul * mul) return;
    int u = idx >> shift;
    int w = idx - (u << shift);
    int nkb = mul >> 5;
    int cb = w >> 4, kb = u >> 5;
    int lane = ((u >> 3) & 3) * 16 + (w & 15);
    int j = u & 7;
    unsigned uv = __float_as_uint(W[idx] * scale) + 0x8000u;
    dst[(((cb * nkb + kb) * 64 + lane) << 3) + j] = (unsigned short)(uv >> 16);
}

// Single prep launch: blocks [0,256) -> W0, [256,320) -> W1, [320,336) -> W2.
__global__ __launch_bounds__(256) void prep_all(const float* __restrict__ W0,
                                                const float* __restrict__ W1,
                                                const float* __restrict__ W2,
                                                unsigned short* __restrict__ wf) {
    int b = blockIdx.x;
    if (b < 256)      prep_one(W0, wf,         256, 8, 0.0625f,              b * 256 + threadIdx.x);
    else if (b < 320) prep_one(W1, wf + 65536, 128, 7, 0.08838834764831845f, (b - 256) * 256 + threadIdx.x);
    else              prep_one(W2, wf + 81920, 64,  6, 0.125f,               (b - 320) * 256 + threadIdx.x);
}

// Read 2*D swizzled 16B chunks of row `lrow` starting at logical chunk c0,
// de-interleave by d into D A-fragments (elem j = x[u_octet_base + j][d]).
template <int D>
__device__ __forceinline__ void pack_from_lds(const float* __restrict__ lrow, int xr, int c0,
                                              short8* __restrict__ out) {
    float buf[8 * D];
#pragma unroll
    for (int v = 0; v < 2 * D; ++v) {
        f32x4 t = *reinterpret_cast<const f32x4*>(lrow + (((c0 + v) ^ xr) << 2));
        buf[v * 4 + 0] = t[0]; buf[v * 4 + 1] = t[1];
        buf[v * 4 + 2] = t[2]; buf[v * 4 + 3] = t[3];
    }
#pragma unroll
    for (int d = 0; d < D; ++d) {
        union { short8 s8; unsigned u[4]; } fr;
#pragma unroll
        for (int jj = 0; jj < 4; ++jj)
            fr.u[jj] = pack2bf(buf[(2 * jj) * D + d], buf[(2 * jj + 1) * D + d]);
        out[d] = fr.s8;
    }
}

// Deterministic scalar store (exact vmcnt accounting): 1 VMEM op, imm offset (BYTES).
#define ST(p, val, imm) \
    asm volatile("global_store_dword %0, %1, off offset:" imm :: "v"(p), "v"(val) : "memory")

// grid = 256 blocks (1/CU, LDS-limited), 4 waves/block. Block owns a contiguous
// run of 16-row tiles. Iteration: STAGE(k+1) -> compute(k) -> 60 asm stores ->
// vmcnt(60) [= stage(k+1) resident; never blocks on tile-k stores] -> barrier.
// Stores older than stage(k+1) get a full tile (~15k cyc) to drain in background.
__global__ __launch_bounds__(256, 1) void lin_main(const float* __restrict__ in,
                                                   const unsigned short* __restrict__ wf0,
                                                   const unsigned short* __restrict__ wf1,
                                                   const unsigned short* __restrict__ wf2,
                                                   const float* __restrict__ bias,
                                                   float* __restrict__ out) {
    __shared__ float lds[2][15360];  // 2 x 16 rows x 960 f32 = 122880 B
    const int w = threadIdx.x >> 6;
    const int lane = threadIdx.x & 63;
    const int lm = lane & 15, lg = lane >> 4, xr = lm & 7;

    // ---- register(AGPR)-resident B fragments (whole W, split by cb across waves)
    short8 b0[4][8], b1[2][4], b2[2];
#pragma unroll
    for (int c = 0; c < 4; ++c)
#pragma unroll
        for (int kb = 0; kb < 8; ++kb)
            b0[c][kb] = *reinterpret_cast<const short8*>(wf0 + ((((w * 4 + c) * 8 + kb) * 64 + lane) << 3));
#pragma unroll
    for (int c = 0; c < 2; ++c)
#pragma unroll
        for (int kb = 0; kb < 4; ++kb)
            b1[c][kb] = *reinterpret_cast<const short8*>(wf1 + ((((w * 2 + c) * 4 + kb) * 64 + lane) << 3));
#pragma unroll
    for (int kb = 0; kb < 2; ++kb)
        b2[kb] = *reinterpret_cast<const short8*>(wf2 + (((w * 2 + kb) * 64 + lane) << 3));
    float bv[4];
#pragma unroll
    for (int c = 0; c < 4; ++c) bv[c] = bias[(w * 4 + c) * 16 + lm];

    // ---- per-lane staging source offsets (bytes from tile base), pre-swizzled:
    // LDS slot (row,c) <- global chunk (row, c ^ (row&7)); slot = w*960 + i*64 + lane.
    int srcoff[15];
#pragma unroll
    for (int i = 0; i < 15; ++i) {
        int s = w * 960 + i * 64 + lane;
        int row = (int)(((long long)s * 17477) >> 22);  // s / 240
        int c = s - row * 240;
        srcoff[i] = (row * 240 + (c ^ (row & 7))) << 4;
    }

    const int b = blockIdx.x;
    const int nt = (b < 106) ? 25 : 24;          // 6250 tiles over 256 blocks
    const int t0 = b * 24 + (b < 106 ? b : 106); // contiguous tile range

#define STAGE(kk, bufi)                                                                   \
    {                                                                                     \
        const char* tb = (const char*)in + (size_t)(t0 + (kk)) * 61440;                   \
        char* sd = (char*)&lds[0][0] + (bufi) * 61440 + w * 15360;                        \
        _Pragma("unroll")                                                                 \
        for (int i = 0; i < 15; ++i)                                                      \
            __builtin_amdgcn_global_load_lds(                                             \
                (const __attribute__((address_space(1))) void*)(tb + srcoff[i]),          \
                (__attribute__((address_space(3))) void*)(sd + i * 1024), 16, 0, 0);      \
    }

    // ---- prologue: stage tile 0, drain, sync
    STAGE(0, 0);
    asm volatile("s_waitcnt vmcnt(0)" ::: "memory");
    __builtin_amdgcn_s_barrier();
    __builtin_amdgcn_sched_barrier(0);

    for (int k = 0; k < nt; ++k) {
        const int par = k & 1;
        if (k + 1 < nt) STAGE(k + 1, par ^ 1);  // loads lead compute by a full phase

        // ---- compute tile k from LDS buf[par]: all accumulators first
        const float* lrow = &lds[0][0] + par * 15360 + lm * 960;
        const int trow = (t0 + k) * 16;

        short8 a0[8];
#pragma unroll
        for (int kb = 0; kb < 8; ++kb)
            pack_from_lds<1>(lrow, xr, 8 * kb + 2 * lg, &a0[kb]);
        f32x4 acc0[4];
#pragma unroll
        for (int c = 0; c < 4; ++c) {
            f32x4 z = {0.f, 0.f, 0.f, 0.f};
#pragma unroll
            for (int kb = 0; kb < 8; ++kb)
                z = __builtin_amdgcn_mfma_f32_16x16x32_bf16(a0[kb], b0[c][kb], z, 0, 0, 0);
            acc0[c] = z;
        }
        short8 a1[4][3];
#pragma unroll
        for (int kb = 0; kb < 4; ++kb)
            pack_from_lds<3>(lrow, xr, 64 + 24 * kb + 6 * lg, a1[kb]);
        f32x4 acc1[2][3];
#pragma unroll
        for (int c = 0; c < 2; ++c)
#pragma unroll
            for (int d = 0; d < 3; ++d) {
                f32x4 z = {0.f, 0.f, 0.f, 0.f};
#pragma unroll
                for (int kb = 0; kb < 4; ++kb)
                    z = __builtin_amdgcn_mfma_f32_16x16x32_bf16(a1[kb][d], b1[c][kb], z, 0, 0, 0);
                acc1[c][d] = z;
            }
        short8 a2[2][5];
#pragma unroll
        for (int kb = 0; kb < 2; ++kb)
            pack_from_lds<5>(lrow, xr, 160 + 40 * kb + 10 * lg, a2[kb]);
        f32x4 acc2[5];
#pragma unroll
        for (int d = 0; d < 5; ++d) {
            f32x4 z = {0.f, 0.f, 0.f, 0.f};
#pragma unroll
            for (int kb = 0; kb < 2; ++kb)
                z = __builtin_amdgcn_mfma_f32_16x16x32_bf16(a2[kb][d], b2[kb], z, 0, 0, 0);
            acc2[d] = z;
        }

        // ---- 60 deterministic stores (15 per output row jj); imm offsets in BYTES
        // D/C layout: col = lane&15, row = (lane>>4)*4 + reg  (m89-verified)
#pragma unroll
        for (int jj = 0; jj < 4; ++jj) {
            float* r = out + (size_t)(trow + lg * 4 + jj) * 960;
            float* p0 = r + w * 64 + lm;                 // blk0: cols (w*4+c)*16+lm, c-stride 16 fl = 64 B
            ST(p0, acc0[0][jj] + bv[0], "0");
            ST(p0, acc0[1][jj] + bv[1], "64");
            ST(p0, acc0[2][jj] + bv[2], "128");
            ST(p0, acc0[3][jj] + bv[3], "192");
            float* p1 = r + 256 + (w * 32 + lm) * 3;     // blk1: c-stride 48 fl = 192 B, d-stride 4 B
            ST(p1, acc1[0][0][jj], "0");
            ST(p1, acc1[0][1][jj], "4");
            ST(p1, acc1[0][2][jj], "8");
            ST(p1, acc1[1][0][jj], "192");
            ST(p1, acc1[1][1][jj], "196");
            ST(p1, acc1[1][2][jj], "200");
            float* p2 = r + 640 + (w * 16 + lm) * 5;     // blk2: d-stride 4 B
            ST(p2, acc2[0][jj], "0");
            ST(p2, acc2[1][jj], "4");
            ST(p2, acc2[2][jj], "8");
            ST(p2, acc2[3][jj], "12");
            ST(p2, acc2[4][jj], "16");
        }

        __builtin_amdgcn_sched_barrier(0);
        if (k + 1 < nt)  // suffix after stage(k+1) = exactly the 60 stores above
            asm volatile("s_waitcnt vmcnt(60)" ::: "memory");
        __builtin_amdgcn_s_barrier();   // buf[par] reads done + everyone's stage(k+1) resident
        __builtin_amdgcn_sched_barrier(0);
    }
#undef STAGE
}

extern "C" void kernel_launch(void* const* d_in, const int* in_sizes, int n_in,
                              void* d_out, int out_size, void* d_ws, size_t ws_size,
                              hipStream_t stream) {
    (void)in_sizes; (void)n_in; (void)out_size; (void)ws_size;
    const float* x  = (const float*)d_in[0];
    const float* W0 = (const float*)d_in[1];
    const float* W1 = (const float*)d_in[2];
    const float* W2 = (const float*)d_in[3];
    const float* b  = (const float*)d_in[4];
    float* out = (float*)d_out;
    unsigned short* wf = (unsigned short*)d_ws;  // 65536 + 16384 + 4096 bf16 = 168 KB

    prep_all<<<336, 256, 0, stream>>>(W0, W1, W2, wf);
    lin_main<<<256, 256, 0, stream>>>(x, wf, wf + 65536, wf + 81920, b, out);
}